// Round 1
// 717.177 us; speedup vs baseline: 1.2786x; 1.2786x over previous
//
#include <hip/hip_runtime.h>

#define B 8
#define CIN 64
#define COUT 128
#define H 256
#define W 256
#define HW 65536
#define OH 128
#define OW 128

typedef __attribute__((ext_vector_type(8))) short bf16x8;
typedef __attribute__((ext_vector_type(16))) float f32x16;
typedef __attribute__((ext_vector_type(4))) float f32x4;
typedef __attribute__((ext_vector_type(2))) float f32x2;

// CDF 9/7 analysis filters
__constant__ float c_h0[9] = {0.026748757410810f, -0.016864118442875f, -0.078223266528990f,
                              0.266864118442875f, 0.602949018236360f, 0.266864118442875f,
                              -0.078223266528990f, -0.016864118442875f, 0.026748757410810f};
__constant__ float c_h1[7] = {0.091271763114250f, -0.057543526228500f, -0.591271763114250f,
                              1.115087052457000f, -0.591271763114250f, -0.057543526228500f,
                              0.091271763114250f};

__device__ __forceinline__ unsigned short f2bf(float f) {
    unsigned int x = __float_as_uint(f);
    unsigned int r = (x + 0x7fffu + ((x >> 16) & 1u)) >> 16;  // RNE, inputs finite
    return (unsigned short)r;
}
__device__ __forceinline__ float bf2f(unsigned short h) {
    return __uint_as_float(((unsigned int)h) << 16);
}
__device__ __forceinline__ int refl(int i) {
    if (i < 0) return -i;
    if (i > 255) return 510 - i;
    return i;
}

// ---------------------------------------------------------------- sigma
__global__ void sigma_kernel(const float* __restrict__ w, const float* __restrict__ u,
                             float* __restrict__ inv_sigma) {
    __shared__ float v[576];
    __shared__ float red[256];
    const int tid = threadIdx.x;
    for (int j = tid; j < 576; j += 256) {
        float s = 0.f;
        for (int o = 0; o < 128; ++o) s += w[o * 576 + j] * u[o];
        v[j] = s;
    }
    __syncthreads();
    float s = 0.f;
    for (int j = tid; j < 576; j += 256) s += v[j] * v[j];
    red[tid] = s;
    __syncthreads();
    for (int off = 128; off > 0; off >>= 1) {
        if (tid < off) red[tid] += red[tid + off];
        __syncthreads();
    }
    const float vn = sqrtf(red[0]) + 1e-12f;
    __syncthreads();
    float tacc = 0.f;
    if (tid < 128) {
        float d = 0.f;
        for (int j = 0; j < 576; ++j) d += w[tid * 576 + j] * v[j];
        d /= vn;
        tacc = d * d;
    }
    red[tid] = tacc;
    __syncthreads();
    for (int off = 128; off > 0; off >>= 1) {
        if (tid < off) red[tid] += red[tid + off];
        __syncthreads();
    }
    if (tid == 0) inv_sigma[0] = 1.f / sqrtf(red[0]);
}

// ---------------------------------------------------------------- prep
// wt_bf[(o*9+tap)*64 + c] = bf16(w_sn[o][c][tap]); gamma_bf[o*128+c] = bf16(gamma)
__global__ void prep_kernel(const float* __restrict__ w, const float* __restrict__ gamma,
                            const float* __restrict__ inv_sigma,
                            unsigned short* __restrict__ wt_bf,
                            unsigned short* __restrict__ gamma_bf) {
    const int i = blockIdx.x * 256 + threadIdx.x;
    const float is = inv_sigma[0];
    if (i < 73728) {
        const int o = i / 576, rem = i - o * 576;
        const int c = rem / 9, tap = rem - c * 9;
        wt_bf[(o * 9 + tap) * 64 + c] = f2bf(w[i] * is);
    } else if (i < 90112) {
        const int j = i - 73728;
        gamma_bf[j] = f2bf(gamma[j]);
    }
}

// ---------------------------------------------------------------- fused conv3x3 + partial renorm + GDN (MFMA)
// block: 256 thr = 4 waves. tile: 4 rows x 32 px, all 128 oc.
// LDS: ONE aliased region for raw (26112 B) / y2 (34816 B) / ygdn (33792 B),
// which are live in disjoint phases separated by barriers. Total 36144 B
// -> 3-4 blocks/CU instead of 2 (the old 70 KB layout was the occupancy cap).
__global__ __launch_bounds__(256, 3) void convgdn_kernel(
    const float* __restrict__ x, const float* __restrict__ mask,
    const unsigned short* __restrict__ wt_bf, const float* __restrict__ bias,
    const unsigned short* __restrict__ gamma_bf, const float* __restrict__ beta,
    unsigned short* __restrict__ t, float* __restrict__ valid) {
    __shared__ __align__(16) char lds[36144];
    unsigned short* raw  = (unsigned short*)lds;            // [6][8cblk][34col][8c]
    unsigned short* y2   = (unsigned short*)lds;            // [128px][136c]   (aliases raw)
    unsigned short* ygdn = (unsigned short*)lds;            // [128oc][132px]  (aliases y2)
    float* mlds = (float*)(lds + 34816);                    // [6][34]
    float* rlds = (float*)(lds + 35632);                    // [128] ratio (0 if invalid)

    const int tid = threadIdx.x;
    const int lane = tid & 63;
    const int lo = lane & 31;
    const int hi = lane >> 5;
    const int n0 = (tid >> 6) << 5;
    const int oc = n0 + lo;  // this lane's output channel (all tiles)
    const int b = blockIdx.z;
    const int h0 = blockIdx.y << 2;
    const int wc0 = blockIdx.x << 5;

    // stage mask tile [6][34] (zero-pad outside image)
    if (tid < 204) {
        const int r = tid / 34, cl = tid - r * 34;
        const int hr = h0 - 1 + r, wc = wc0 - 1 + cl;
        float mv = 0.f;
        if (hr >= 0 && hr < H && wc >= 0 && wc < W) mv = mask[b * HW + hr * W + wc];
        mlds[tid] = mv;
    }
    __syncthreads();

    // stage xm = x*mask as bf16 into raw[r][c>>3][col][c&7]; compute ratio
    // interior blocks (72%) skip all per-element bounds checks
    const bool intr = (h0 != 0) && (h0 != 252) && (wc0 != 0) && (wc0 != 224);
    if (intr) {
        const float* xb = x + b * CIN * HW + (h0 - 1) * W + (wc0 - 1);
        for (unsigned i = tid; i < 13056u; i += 256u) {
            const unsigned c = i / 204u, rem = i - c * 204u;
            const unsigned r = rem / 34u, cl = rem - r * 34u;
            const float v = xb[c * HW + r * W + cl] * mlds[rem];
            raw[((r * 8u + (c >> 3)) * 34u + cl) * 8u + (c & 7u)] = f2bf(v);
        }
    } else {
        for (unsigned i = tid; i < 13056u; i += 256u) {
            const unsigned c = i / 204u, rem = i - c * 204u;
            const unsigned r = rem / 34u, cl = rem - r * 34u;
            const int hr = h0 - 1 + (int)r, wc = wc0 - 1 + (int)cl;
            float v = 0.f;
            if (hr >= 0 && hr < H && wc >= 0 && wc < W)
                v = x[((b * CIN + (int)c) * H + hr) * W + wc] * mlds[rem];
            raw[((r * 8u + (c >> 3)) * 34u + cl) * 8u + (c & 7u)] = f2bf(v);
        }
    }
    if (tid < 128) {
        const int mt = tid >> 5, cl = tid & 31;
        float ms = 0.f;
#pragma unroll
        for (int a = 0; a < 3; ++a)
#pragma unroll
            for (int bb = 0; bb < 3; ++bb) ms += mlds[(mt + a) * 34 + cl + bb];
        const bool vld = ms > 0.f;
        rlds[tid] = vld ? 9.f / fmaxf(ms, 1e-8f) : 0.f;
        valid[b * HW + (h0 + mt) * W + wc0 + cl] = vld ? 1.f : 0.f;
    }
    __syncthreads();

    // ---- conv implicit GEMM: K = 9 taps x 64 c (tap-major, c-fastest)
    // tap-outer loop; the 4 per-tap weight loads are batched for MLP
    f32x16 acc[4];
#pragma unroll
    for (int mt = 0; mt < 4; ++mt)
#pragma unroll
        for (int r = 0; r < 16; ++r) acc[mt][r] = 0.f;

    for (int kh = 0; kh < 3; ++kh) {
#pragma unroll
        for (int kw = 0; kw < 3; ++kw) {
            const int tap = kh * 3 + kw;
            bf16x8 bw[4];
#pragma unroll
            for (int cc = 0; cc < 4; ++cc)
                bw[cc] = *(const bf16x8*)&wt_bf[(oc * 9 + tap) * 64 + cc * 16 + hi * 8];
#pragma unroll
            for (int cc = 0; cc < 4; ++cc) {
                const int c0 = cc * 16 + hi * 8;
#pragma unroll
                for (int mt = 0; mt < 4; ++mt) {
                    const bf16x8 afrag =
                        *(const bf16x8*)&raw[(((mt + kh) * 8 + (c0 >> 3)) * 34 + (lo + kw)) * 8];
                    acc[mt] = __builtin_amdgcn_mfma_f32_32x32x16_bf16(afrag, bw[cc], acc[mt], 0, 0, 0);
                }
            }
        }
    }
    __syncthreads();  // all raw reads done before y2 overwrites the region

    // ---- epilogue: y = valid ? acc*ratio + bias : 0 ; write y^2 (bf16) to y2[px][c]
    const float bs = bias[oc];
    const float bt = beta[oc];
#pragma unroll
    for (int mt = 0; mt < 4; ++mt) {
#pragma unroll
        for (int r = 0; r < 16; ++r) {
            const int rowq = (r & 3) + 8 * (r >> 2) + 4 * hi;  // pixel col within tile
            const float rat = rlds[mt * 32 + rowq];
            const float y = (rat > 0.f) ? acc[mt][r] * rat + bs : 0.f;
            acc[mt][r] = y;  // keep y in regs
            y2[(mt * 32 + rowq) * 136 + oc] = f2bf(y * y);
        }
    }
    __syncthreads();

    // ---- GDN MFMA: denom_acc[px][o] = sum_c gamma[o][c] * y2[px][c], K=128 in 8 chunks
    f32x16 acc2[4];
#pragma unroll
    for (int g = 0; g < 4; ++g)
#pragma unroll
        for (int r = 0; r < 16; ++r) acc2[g][r] = 0.f;

    for (int ch = 0; ch < 8; ++ch) {
        const int c0 = ch * 16 + hi * 8;
        const bf16x8 gb = *(const bf16x8*)&gamma_bf[oc * 128 + c0];
#pragma unroll
        for (int g = 0; g < 4; ++g) {
            const bf16x8 ga = *(const bf16x8*)&y2[(g * 32 + lo) * 136 + c0];
            acc2[g] = __builtin_amdgcn_mfma_f32_32x32x16_bf16(ga, gb, acc2[g], 0, 0, 0);
        }
    }
    __syncthreads();  // all y2 reads done before ygdn overwrites the region

    // ---- final: y_gdn = y * rsqrt(beta + denom); write to ygdn[oc][px] (LDS transpose)
#pragma unroll
    for (int mt = 0; mt < 4; ++mt) {
#pragma unroll
        for (int rg = 0; rg < 4; ++rg) {
            const int base = 8 * rg + 4 * hi;
            ushort4 pk;
            unsigned short* pp = (unsigned short*)&pk;
#pragma unroll
            for (int j = 0; j < 4; ++j) {
                const int r = rg * 4 + j;
                const float d = bt + acc2[mt][r];
                pp[j] = f2bf(acc[mt][r] * rsqrtf(d));
            }
            *(ushort4*)&ygdn[oc * 132 + mt * 32 + base] = pk;
        }
    }
    __syncthreads();

    // ---- coalesced dump: each thread writes one 64-B row-run (32 px) of one oc
#pragma unroll
    for (int it = 0; it < 2; ++it) {
        const int idx = it * 256 + tid;
        const int oc2 = idx >> 2, mt2 = idx & 3;
        const unsigned short* src = &ygdn[oc2 * 132 + mt2 * 32];
        unsigned short* dst = &t[((b * COUT + oc2) * H + h0 + mt2) * W + wc0];
#pragma unroll
        for (int k = 0; k < 8; ++k)
            *(ushort4*)(dst + k * 4) = *(const ushort4*)(src + k * 4);
    }
}

// ---------------------------------------------------------------- fused DWT (4 subbands)
// vectorized rewrite: ushort4 staging, float4 LDS filter passes, float2 stores
__global__ void dwt_kernel(const unsigned short* __restrict__ y, float* __restrict__ out) {
    __shared__ float ys[40][76];  // 76 pad: row stride 304 B = 19 granules (odd)
    __shared__ float lof[16][76];
    __shared__ float hif[16][76];
    const int tid = threadIdx.x;
    const int wt_ = blockIdx.x & 3;
    const int ht_ = blockIdx.x >> 2;
    const int bc = blockIdx.y;
    const int ho0 = ht_ * 16, wo0 = wt_ * 32;
    const int r0 = 2 * ho0 - 4, c0 = 2 * wo0 - 4;
    const unsigned short* yb = y + bc * HW;

    // stage: 40 rows x 18 ushort4 chunks (c0 = 64*wt_-4 is 4-aligned -> 8-B loads)
    for (unsigned i = tid; i < 720u; i += 256u) {
        const int lr = (int)(i / 18u);
        const int ch4 = (int)(i - (unsigned)lr * 18u) << 2;
        const int gr = refl(r0 + lr);
        const int col = c0 + ch4;
        const int colc = col < 0 ? 0 : (col > 252 ? 252 : col);
        const ushort4 v = *(const ushort4*)(yb + gr * W + colc);
        if (col == colc) {  // skip the (at most one) out-of-range edge chunk
            f32x4 f;
            f.x = bf2f(v.x); f.y = bf2f(v.y); f.z = bf2f(v.z); f.w = bf2f(v.w);
            *(f32x4*)&ys[lr][ch4] = f;
        }
    }
    // scalar column-reflect fixups: only the two edge tile columns, 4 cols x 40 rows
    if (wt_ == 0) {
        for (int i = tid; i < 160; i += 256) {
            const int lr = i >> 2, q = i & 3;  // col = q-4 -> refl = 4-q
            ys[lr][q] = bf2f(yb[refl(r0 + lr) * W + (4 - q)]);
        }
    } else if (wt_ == 3) {
        for (int i = tid; i < 160; i += 256) {
            const int lr = i >> 2, q = i & 3;  // col = 256+q -> refl = 254-q
            ys[lr][68 + q] = bf2f(yb[refl(r0 + lr) * W + (254 - q)]);
        }
    }
    __syncthreads();

    // vertical filter: 16 rows x 18 float4 chunks; 9 reads produce both lo and hi
    for (unsigned i = tid; i < 288u; i += 256u) {
        const int r = (int)(i / 18u);
        const int ch4 = (int)(i - (unsigned)r * 18u) << 2;
        f32x4 vv[9];
#pragma unroll
        for (int k = 0; k < 9; ++k) vv[k] = *(const f32x4*)&ys[2 * r + k][ch4];
        f32x4 sl = c_h0[0] * vv[0];
#pragma unroll
        for (int k = 1; k < 9; ++k) sl += c_h0[k] * vv[k];
        f32x4 sh = c_h1[0] * vv[1];
#pragma unroll
        for (int k = 1; k < 7; ++k) sh += c_h1[k] * vv[k + 1];
        *(f32x4*)&lof[r][ch4] = sl;
        *(f32x4*)&hif[r][ch4] = sh;
    }
    __syncthreads();

    // horizontal: each thread -> 2 output px x 4 subbands from 6 float4 reads
    const int rr = tid >> 4;
    const int q = tid & 15;
    const f32x4 a0 = *(const f32x4*)&lof[rr][4 * q];
    const f32x4 a1 = *(const f32x4*)&lof[rr][4 * q + 4];
    const f32x4 a2 = *(const f32x4*)&lof[rr][4 * q + 8];
    const f32x4 b0 = *(const f32x4*)&hif[rr][4 * q];
    const f32x4 b1 = *(const f32x4*)&hif[rr][4 * q + 4];
    const f32x4 b2 = *(const f32x4*)&hif[rr][4 * q + 8];
    float L[12], M[12];
#pragma unroll
    for (int m = 0; m < 4; ++m) {
        L[m] = a0[m]; L[m + 4] = a1[m]; L[m + 8] = a2[m];
        M[m] = b0[m]; M[m + 4] = b1[m]; M[m + 8] = b2[m];
    }
    float ll0 = 0.f, ll1 = 0.f, hl0 = 0.f, hl1 = 0.f;
#pragma unroll
    for (int k = 0; k < 9; ++k) {
        ll0 += c_h0[k] * L[k];
        ll1 += c_h0[k] * L[k + 2];
        hl0 += c_h0[k] * M[k];
        hl1 += c_h0[k] * M[k + 2];
    }
    float lh0 = 0.f, lh1 = 0.f, hh0 = 0.f, hh1 = 0.f;
#pragma unroll
    for (int k = 0; k < 7; ++k) {
        lh0 += c_h1[k] * L[k + 1];
        lh1 += c_h1[k] * L[k + 3];
        hh0 += c_h1[k] * M[k + 1];
        hh1 += c_h1[k] * M[k + 3];
    }
    const int idx = (bc * OH + ho0 + rr) * OW + wo0 + 2 * q;
    f32x2 s;
    s.x = ll0; s.y = ll1; *(f32x2*)&out[idx] = s;
    s.x = lh0; s.y = lh1; *(f32x2*)&out[16908288 + idx] = s;
    s.x = hl0; s.y = hl1; *(f32x2*)&out[33685504 + idx] = s;
    s.x = hh0; s.y = hh1; *(f32x2*)&out[50462720 + idx] = s;
}

// ---------------------------------------------------------------- DWT masks
__global__ void dwtmask_kernel(const float* __restrict__ valid, float* __restrict__ out) {
    const int g = blockIdx.x * 256 + threadIdx.x;  // 0..131071
    const int b = g >> 14;
    const int rem = g & 16383;
    const int i = rem >> 7, j = rem & 127;
    const float* vb = valid + b * HW;
    bool bll = false, blh = false, bhl = false, bhh = false;
    for (int k1 = 0; k1 < 9; ++k1) {
        const int rr = refl(2 * i - 4 + k1);
        const bool in7r = (k1 >= 1 && k1 <= 7);
        for (int k2 = 0; k2 < 9; ++k2) {
            const int cc = refl(2 * j - 4 + k2);
            if (vb[rr * W + cc] > 0.f) {
                const bool in7c = (k2 >= 1 && k2 <= 7);
                bll = true;
                blh |= in7c;
                bhl |= in7r;
                bhh |= (in7r && in7c);
            }
        }
    }
    out[16777216 + g] = bll ? 1.f : 0.f;  // m_ll
    out[67239936 + g] = blh ? 1.f : 0.f;  // m_lh
    out[67371008 + g] = bhl ? 1.f : 0.f;  // m_hl
    out[67502080 + g] = bhh ? 1.f : 0.f;  // m_hh
}

// ---------------------------------------------------------------- launch
extern "C" void kernel_launch(void* const* d_in, const int* in_sizes, int n_in,
                              void* d_out, int out_size, void* d_ws, size_t ws_size,
                              hipStream_t stream) {
    const float* x     = (const float*)d_in[0];
    const float* mask  = (const float*)d_in[1];
    const float* w     = (const float*)d_in[2];
    const float* bias  = (const float*)d_in[3];
    const float* u     = (const float*)d_in[4];
    const float* beta  = (const float*)d_in[5];
    const float* gamma = (const float*)d_in[6];
    float* out = (float*)d_out;

    float* f_ws = (float*)d_ws;
    float* inv_sigma = f_ws;                                   // 256 floats
    unsigned short* wt_bf    = (unsigned short*)(f_ws + 256);  // 73728 bf16 [o][tap][c]
    unsigned short* gamma_bf = wt_bf + 73728;                  // 16384 bf16 [o][c]
    float* valid = (float*)(gamma_bf + 16384);                 // 524288 fp32 [b][h][w]
    unsigned short* t = (unsigned short*)(valid + 524288);     // bf16 [b][o][h][w]

    sigma_kernel<<<1, 256, 0, stream>>>(w, u, inv_sigma);
    prep_kernel<<<352, 256, 0, stream>>>(w, gamma, inv_sigma, wt_bf, gamma_bf);
    convgdn_kernel<<<dim3(8, 64, 8), 256, 0, stream>>>(x, mask, wt_bf, bias, gamma_bf, beta,
                                                       t, valid);
    dwt_kernel<<<dim3(32, 1024), 256, 0, stream>>>(t, out);
    dwtmask_kernel<<<512, 256, 0, stream>>>(valid, out);
}

// Round 2
// 673.498 us; speedup vs baseline: 1.3615x; 1.0649x over previous
//
#include <hip/hip_runtime.h>

#define B 8
#define CIN 64
#define COUT 128
#define H 256
#define W 256
#define HW 65536
#define OH 128
#define OW 128

typedef __attribute__((ext_vector_type(8))) short bf16x8;
typedef __attribute__((ext_vector_type(16))) float f32x16;
typedef __attribute__((ext_vector_type(4))) float f32x4;
typedef __attribute__((ext_vector_type(2))) float f32x2;

// CDF 9/7 analysis filters
__constant__ float c_h0[9] = {0.026748757410810f, -0.016864118442875f, -0.078223266528990f,
                              0.266864118442875f, 0.602949018236360f, 0.266864118442875f,
                              -0.078223266528990f, -0.016864118442875f, 0.026748757410810f};
__constant__ float c_h1[7] = {0.091271763114250f, -0.057543526228500f, -0.591271763114250f,
                              1.115087052457000f, -0.591271763114250f, -0.057543526228500f,
                              0.091271763114250f};

__device__ __forceinline__ unsigned short f2bf(float f) {
    unsigned int x = __float_as_uint(f);
    unsigned int r = (x + 0x7fffu + ((x >> 16) & 1u)) >> 16;  // RNE, inputs finite
    return (unsigned short)r;
}
__device__ __forceinline__ float bf2f(unsigned short h) {
    return __uint_as_float(((unsigned int)h) << 16);
}
__device__ __forceinline__ int refl(int i) {
    if (i < 0) return -i;
    if (i > 255) return 510 - i;
    return i;
}

// ---------------------------------------------------------------- sigma
// 1024 threads: phase A 576 lanes (coalesced per-o row reads); phase C split
// 8-way per output row with float4 loads (was 128 lanes x 576 scalar loads).
__global__ void sigma_kernel(const float* __restrict__ w, const float* __restrict__ u,
                             float* __restrict__ inv_sigma) {
    __shared__ float v[576];
    __shared__ float red[1024];
    __shared__ float d2[128];
    const int tid = threadIdx.x;
    if (tid < 576) {
        float s = 0.f;
        for (int o = 0; o < 128; ++o) s += w[o * 576 + tid] * u[o];
        v[tid] = s;
    }
    __syncthreads();
    red[tid] = (tid < 576) ? v[tid] * v[tid] : 0.f;
    __syncthreads();
    for (int off = 512; off > 0; off >>= 1) {
        if (tid < off) red[tid] += red[tid + off];
        __syncthreads();
    }
    const float vn = sqrtf(red[0]) + 1e-12f;
    __syncthreads();
    const int o = tid >> 3, p = tid & 7;
    const float* wr = w + o * 576 + p * 72;
    const float* vv = v + p * 72;
    float part = 0.f;
    for (int j = 0; j < 72; j += 4) {
        const f32x4 wv = *(const f32x4*)(wr + j);
        part += wv.x * vv[j] + wv.y * vv[j + 1] + wv.z * vv[j + 2] + wv.w * vv[j + 3];
    }
    red[tid] = part;
    __syncthreads();
    if (tid < 128) {
        float d = 0.f;
        for (int k = 0; k < 8; ++k) d += red[tid * 8 + k];
        d /= vn;
        d2[tid] = d * d;
    }
    __syncthreads();
    for (int off = 64; off > 0; off >>= 1) {
        if (tid < off) d2[tid] += d2[tid + off];
        __syncthreads();
    }
    if (tid == 0) inv_sigma[0] = 1.f / sqrtf(d2[0]);
}

// ---------------------------------------------------------------- prep
__global__ void prep_kernel(const float* __restrict__ w, const float* __restrict__ gamma,
                            const float* __restrict__ inv_sigma,
                            unsigned short* __restrict__ wt_bf,
                            unsigned short* __restrict__ gamma_bf) {
    const int i = blockIdx.x * 256 + threadIdx.x;
    const float is = inv_sigma[0];
    if (i < 73728) {
        const int o = i / 576, rem = i - o * 576;
        const int c = rem / 9, tap = rem - c * 9;
        wt_bf[(o * 9 + tap) * 64 + c] = f2bf(w[i] * is);
    } else if (i < 90112) {
        const int j = i - 73728;
        gamma_bf[j] = f2bf(gamma[j]);
    }
}

// ---------------------------------------------------------------- fused conv3x3 + partial renorm + GDN (MFMA)
// block: 256 thr = 4 waves. tile: 4 rows x 32 px, all 128 oc.
// Register diet: GDN fused per M-tile so only ONE f32x16 denom acc is live
// (acc2[4] was 64 extra regs -> VGPR+AGPR was the occupancy cap at 2.4 w/SIMD).
// The y2 row block freed after mt's GDN reads (9216 B) is reused as that mt's
// transpose buffer (stride 36 -> exact partition), one barrier per mt.
// y2: stride 144 + XOR col swizzle -> conflict-free ds_read_b128 in GDN.
__global__ __launch_bounds__(256, 3) void convgdn_kernel(
    const float* __restrict__ x, const float* __restrict__ mask,
    const unsigned short* __restrict__ wt_bf, const float* __restrict__ bias,
    const unsigned short* __restrict__ gamma_bf, const float* __restrict__ beta,
    unsigned short* __restrict__ t, float* __restrict__ valid) {
    __shared__ __align__(16) char lds[38192];
    unsigned short* raw = (unsigned short*)lds;   // [6][8cblk][34col][8c] = 26112 B
    unsigned short* y2  = (unsigned short*)lds;   // [128px][144c swz] = 36864 B (alias)
    float* mlds = (float*)(lds + 36864);          // [6][34]
    float* rlds = (float*)(lds + 37680);          // [128] ratio (0 if invalid)

    const int tid = threadIdx.x;
    const int lane = tid & 63;
    const int lo = lane & 31;
    const int hi = lane >> 5;
    const int n0 = (tid >> 6) << 5;
    const int oc = n0 + lo;
    // XCD-aware swizzle: each XCD gets one full batch image (512 contiguous works)
    const int bid = blockIdx.x;
    const int work = ((bid & 7) << 9) | (bid >> 3);
    const int b = work >> 9;
    const int rem0 = work & 511;
    const int h0 = (rem0 >> 3) << 2;
    const int wc0 = (rem0 & 7) << 5;

    // stage mask tile [6][34] (zero-pad outside image)
    if (tid < 204) {
        const int r = tid / 34, cl = tid - r * 34;
        const int hr = h0 - 1 + r, wc = wc0 - 1 + cl;
        float mv = 0.f;
        if (hr >= 0 && hr < H && wc >= 0 && wc < W) mv = mask[b * HW + hr * W + wc];
        mlds[tid] = mv;
    }
    __syncthreads();

    // stage xm = x*mask as bf16 into raw[r][c>>3][col][c&7]; compute ratio
    const bool intr = (h0 != 0) && (h0 != 252) && (wc0 != 0) && (wc0 != 224);
    if (intr) {
        // vectorized: float4 x 2 channels per item; aligned chunks cover cols
        // wc0-4 .. wc0+35 (interior-safe), only cl in [0,33] is written.
        const float* xb = x + ((size_t)b * CIN) * HW + (h0 - 1) * W + (wc0 - 4);
        for (unsigned i = tid; i < 1920u; i += 256u) {
            const unsigned q = i % 10u;
            const unsigned rc = i / 10u;
            const unsigned r = rc % 6u;
            const unsigned cp = rc / 6u;  // channel pair 0..31
            const float* p0 = xb + (2u * cp) * HW + r * W + 4u * q;
            const f32x4 va = *(const f32x4*)p0;
            const f32x4 vb2 = *(const f32x4*)(p0 + HW);
            unsigned short* base = &raw[((r * 8u + (cp >> 2)) * 34u) * 8u + 2u * (cp & 3u)];
            const float* mrow = &mlds[r * 34u];
#pragma unroll
            for (int k = 0; k < 4; ++k) {
                const int cl = 4 * (int)q - 3 + k;
                if ((unsigned)cl <= 33u) {
                    const float mv = mrow[cl];
                    const unsigned int pk = (unsigned int)f2bf(va[k] * mv) |
                                            ((unsigned int)f2bf(vb2[k] * mv) << 16);
                    *(unsigned int*)(base + (unsigned)cl * 8u) = pk;
                }
            }
        }
    } else {
        for (unsigned i = tid; i < 13056u; i += 256u) {
            const unsigned c = i / 204u, rem = i - c * 204u;
            const unsigned r = rem / 34u, cl = rem - r * 34u;
            const int hr = h0 - 1 + (int)r, wc = wc0 - 1 + (int)cl;
            float v = 0.f;
            if (hr >= 0 && hr < H && wc >= 0 && wc < W)
                v = x[((b * CIN + (int)c) * H + hr) * W + wc] * mlds[rem];
            raw[((r * 8u + (c >> 3)) * 34u + cl) * 8u + (c & 7u)] = f2bf(v);
        }
    }
    if (tid < 128) {
        const int mt = tid >> 5, cl = tid & 31;
        float ms = 0.f;
#pragma unroll
        for (int a = 0; a < 3; ++a)
#pragma unroll
            for (int bb = 0; bb < 3; ++bb) ms += mlds[(mt + a) * 34 + cl + bb];
        const bool vld = ms > 0.f;
        rlds[tid] = vld ? 9.f / fmaxf(ms, 1e-8f) : 0.f;
        valid[b * HW + (h0 + mt) * W + wc0 + cl] = vld ? 1.f : 0.f;
    }
    __syncthreads();

    // ---- conv implicit GEMM: K = 9 taps x 64 c (tap-major, c-fastest)
    f32x16 acc[4];
#pragma unroll
    for (int mt = 0; mt < 4; ++mt)
#pragma unroll
        for (int r = 0; r < 16; ++r) acc[mt][r] = 0.f;

    for (int kh = 0; kh < 3; ++kh) {
#pragma unroll
        for (int kw = 0; kw < 3; ++kw) {
            const int tap = kh * 3 + kw;
            bf16x8 bw[4];
#pragma unroll
            for (int cc = 0; cc < 4; ++cc)
                bw[cc] = *(const bf16x8*)&wt_bf[(oc * 9 + tap) * 64 + cc * 16 + hi * 8];
#pragma unroll
            for (int cc = 0; cc < 4; ++cc) {
                const int c0 = cc * 16 + hi * 8;
#pragma unroll
                for (int mt = 0; mt < 4; ++mt) {
                    const bf16x8 afrag =
                        *(const bf16x8*)&raw[(((mt + kh) * 8 + (c0 >> 3)) * 34 + (lo + kw)) * 8];
                    acc[mt] = __builtin_amdgcn_mfma_f32_32x32x16_bf16(afrag, bw[cc], acc[mt], 0, 0, 0);
                }
            }
        }
    }
    __syncthreads();  // all raw reads done before y2 overwrites the region

    // ---- epilogue: y = valid ? acc*ratio + bias : 0 ; write y^2 (bf16, swizzled)
    const float bs = bias[oc];
    const float bt = beta[oc];
#pragma unroll
    for (int mt = 0; mt < 4; ++mt) {
#pragma unroll
        for (int r = 0; r < 16; ++r) {
            const int rowq = (r & 3) + 8 * (r >> 2) + 4 * hi;  // pixel col within tile
            const float rat = rlds[mt * 32 + rowq];
            const float y = (rat > 0.f) ? acc[mt][r] * rat + bs : 0.f;
            acc[mt][r] = y;  // keep y in regs
            y2[(mt * 32 + rowq) * 144 + (oc ^ ((rowq & 7) << 3))] = f2bf(y * y);
        }
    }
    __syncthreads();

    // ---- GDN per M-tile: denom = gamma @ y2 (8 MFMA), then write transpose
    // block into the y2 rows just freed.
#pragma unroll
    for (int mt = 0; mt < 4; ++mt) {
        f32x16 a2;
#pragma unroll
        for (int r = 0; r < 16; ++r) a2[r] = 0.f;
        const int row = mt * 32 + lo;
        const int swz = (lo & 7) << 3;
#pragma unroll
        for (int ch = 0; ch < 8; ++ch) {
            const int c0 = ch * 16 + hi * 8;
            const bf16x8 gb = *(const bf16x8*)&gamma_bf[oc * 128 + c0];
            const bf16x8 ga = *(const bf16x8*)&y2[row * 144 + (c0 ^ swz)];
            a2 = __builtin_amdgcn_mfma_f32_32x32x16_bf16(ga, gb, a2, 0, 0, 0);
        }
        __syncthreads();  // all waves done reading y2 rows [32mt, 32mt+32)
        unsigned short* yg = (unsigned short*)lds + mt * 4608;  // freed block, [128oc][36px]
#pragma unroll
        for (int rg = 0; rg < 4; ++rg) {
            ushort4 pk;
            unsigned short* pp = (unsigned short*)&pk;
#pragma unroll
            for (int j = 0; j < 4; ++j) {
                const int r = rg * 4 + j;
                const float d = bt + a2[r];
                pp[j] = f2bf(acc[mt][r] * rsqrtf(d));
            }
            const int pxc = 2 * rg + hi;  // 4-px chunk index 0..7
            *(ushort4*)&yg[oc * 36 + ((pxc ^ (oc & 7)) << 2)] = pk;
        }
    }
    __syncthreads();

    // ---- coalesced dump: thread -> (oc2, mt2); 8 x ushort4 per 32-px row-run
#pragma unroll
    for (int it = 0; it < 2; ++it) {
        const int idx = it * 256 + tid;
        const int oc2 = idx & 127, mt2 = idx >> 7;
        const unsigned short* src = (const unsigned short*)lds + mt2 * 4608 + oc2 * 36;
        unsigned short* dst = &t[((b * COUT + oc2) * H + h0 + mt2) * W + wc0];
        const int s7 = oc2 & 7;
#pragma unroll
        for (int k = 0; k < 8; ++k)
            *(ushort4*)(dst + k * 4) = *(const ushort4*)(src + ((k ^ s7) << 2));
    }
}

// ---------------------------------------------------------------- fused DWT (4 subbands)
// staging loads hoisted into registers (3 overlapped HBM latencies, was
// load->cond-LDS-write per iter = serialized); XCD-swizzled 1D grid.
__global__ void dwt_kernel(const unsigned short* __restrict__ y, float* __restrict__ out) {
    __shared__ float ys[40][76];  // 76 pad: row stride 304 B (odd granule)
    __shared__ float lof[16][76];
    __shared__ float hif[16][76];
    const int tid = threadIdx.x;
    const int bid = blockIdx.x;
    const int work = ((bid & 7) << 12) | (bid >> 3);  // XCD gets 128 contiguous channels
    const int bc = work >> 5;
    const int tile = work & 31;
    const int wt_ = tile & 3;
    const int ht_ = tile >> 2;
    const int ho0 = ht_ * 16, wo0 = wt_ * 32;
    const int r0 = 2 * ho0 - 4, c0 = 2 * wo0 - 4;
    const unsigned short* yb = y + bc * HW;

    // stage: 720 ushort4 chunks; loads batched before any LDS write
    ushort4 va[3];
    int ldst[3];
#pragma unroll
    for (int k = 0; k < 3; ++k) {
        const int i = tid + (k << 8);
        ldst[k] = -1;
        if (i < 720) {
            const int lr = i / 18;
            const int ch4 = (i - lr * 18) << 2;
            const int col = c0 + ch4;
            if ((unsigned)col <= 252u) {  // skip the (at most one) OOB edge chunk
                va[k] = *(const ushort4*)(yb + refl(r0 + lr) * W + col);
                ldst[k] = lr * 76 + ch4;
            }
        }
    }
#pragma unroll
    for (int k = 0; k < 3; ++k) {
        if (ldst[k] >= 0) {
            f32x4 f;
            f.x = bf2f(va[k].x); f.y = bf2f(va[k].y); f.z = bf2f(va[k].z); f.w = bf2f(va[k].w);
            *(f32x4*)&((float*)ys)[ldst[k]] = f;
        }
    }
    // scalar column-reflect fixups: only the two edge tile columns, 4 cols x 40 rows
    if (wt_ == 0) {
        for (int i = tid; i < 160; i += 256) {
            const int lr = i >> 2, q = i & 3;  // col = q-4 -> refl = 4-q
            ys[lr][q] = bf2f(yb[refl(r0 + lr) * W + (4 - q)]);
        }
    } else if (wt_ == 3) {
        for (int i = tid; i < 160; i += 256) {
            const int lr = i >> 2, q = i & 3;  // col = 256+q -> refl = 254-q
            ys[lr][68 + q] = bf2f(yb[refl(r0 + lr) * W + (254 - q)]);
        }
    }
    __syncthreads();

    // vertical filter: 16 rows x 18 float4 chunks; 9 reads produce both lo and hi
    for (unsigned i = tid; i < 288u; i += 256u) {
        const int r = (int)(i / 18u);
        const int ch4 = (int)(i - (unsigned)r * 18u) << 2;
        f32x4 vv[9];
#pragma unroll
        for (int k = 0; k < 9; ++k) vv[k] = *(const f32x4*)&ys[2 * r + k][ch4];
        f32x4 sl = c_h0[0] * vv[0];
#pragma unroll
        for (int k = 1; k < 9; ++k) sl += c_h0[k] * vv[k];
        f32x4 sh = c_h1[0] * vv[1];
#pragma unroll
        for (int k = 1; k < 7; ++k) sh += c_h1[k] * vv[k + 1];
        *(f32x4*)&lof[r][ch4] = sl;
        *(f32x4*)&hif[r][ch4] = sh;
    }
    __syncthreads();

    // horizontal: each thread -> 2 output px x 4 subbands from 6 float4 reads
    const int rr = tid >> 4;
    const int q = tid & 15;
    const f32x4 a0 = *(const f32x4*)&lof[rr][4 * q];
    const f32x4 a1 = *(const f32x4*)&lof[rr][4 * q + 4];
    const f32x4 a2 = *(const f32x4*)&lof[rr][4 * q + 8];
    const f32x4 b0 = *(const f32x4*)&hif[rr][4 * q];
    const f32x4 b1 = *(const f32x4*)&hif[rr][4 * q + 4];
    const f32x4 b2 = *(const f32x4*)&hif[rr][4 * q + 8];
    float L[12], M[12];
#pragma unroll
    for (int m = 0; m < 4; ++m) {
        L[m] = a0[m]; L[m + 4] = a1[m]; L[m + 8] = a2[m];
        M[m] = b0[m]; M[m + 4] = b1[m]; M[m + 8] = b2[m];
    }
    float ll0 = 0.f, ll1 = 0.f, hl0 = 0.f, hl1 = 0.f;
#pragma unroll
    for (int k = 0; k < 9; ++k) {
        ll0 += c_h0[k] * L[k];
        ll1 += c_h0[k] * L[k + 2];
        hl0 += c_h0[k] * M[k];
        hl1 += c_h0[k] * M[k + 2];
    }
    float lh0 = 0.f, lh1 = 0.f, hh0 = 0.f, hh1 = 0.f;
#pragma unroll
    for (int k = 0; k < 7; ++k) {
        lh0 += c_h1[k] * L[k + 1];
        lh1 += c_h1[k] * L[k + 3];
        hh0 += c_h1[k] * M[k + 1];
        hh1 += c_h1[k] * M[k + 3];
    }
    const int idx = (bc * OH + ho0 + rr) * OW + wo0 + 2 * q;
    f32x2 s;
    s.x = ll0; s.y = ll1; *(f32x2*)&out[idx] = s;
    s.x = lh0; s.y = lh1; *(f32x2*)&out[16908288 + idx] = s;
    s.x = hl0; s.y = hl1; *(f32x2*)&out[33685504 + idx] = s;
    s.x = hh0; s.y = hh1; *(f32x2*)&out[50462720 + idx] = s;
}

// ---------------------------------------------------------------- DWT masks
__global__ void dwtmask_kernel(const float* __restrict__ valid, float* __restrict__ out) {
    const int g = blockIdx.x * 256 + threadIdx.x;  // 0..131071
    const int b = g >> 14;
    const int rem = g & 16383;
    const int i = rem >> 7, j = rem & 127;
    const float* vb = valid + b * HW;
    bool bll = false, blh = false, bhl = false, bhh = false;
    for (int k1 = 0; k1 < 9; ++k1) {
        const int rr = refl(2 * i - 4 + k1);
        const bool in7r = (k1 >= 1 && k1 <= 7);
        for (int k2 = 0; k2 < 9; ++k2) {
            const int cc = refl(2 * j - 4 + k2);
            if (vb[rr * W + cc] > 0.f) {
                const bool in7c = (k2 >= 1 && k2 <= 7);
                bll = true;
                blh |= in7c;
                bhl |= in7r;
                bhh |= (in7r && in7c);
            }
        }
    }
    out[16777216 + g] = bll ? 1.f : 0.f;  // m_ll
    out[67239936 + g] = blh ? 1.f : 0.f;  // m_lh
    out[67371008 + g] = bhl ? 1.f : 0.f;  // m_hl
    out[67502080 + g] = bhh ? 1.f : 0.f;  // m_hh
}

// ---------------------------------------------------------------- launch
extern "C" void kernel_launch(void* const* d_in, const int* in_sizes, int n_in,
                              void* d_out, int out_size, void* d_ws, size_t ws_size,
                              hipStream_t stream) {
    const float* x     = (const float*)d_in[0];
    const float* mask  = (const float*)d_in[1];
    const float* w     = (const float*)d_in[2];
    const float* bias  = (const float*)d_in[3];
    const float* u     = (const float*)d_in[4];
    const float* beta  = (const float*)d_in[5];
    const float* gamma = (const float*)d_in[6];
    float* out = (float*)d_out;

    float* f_ws = (float*)d_ws;
    float* inv_sigma = f_ws;                                   // 256 floats
    unsigned short* wt_bf    = (unsigned short*)(f_ws + 256);  // 73728 bf16 [o][tap][c]
    unsigned short* gamma_bf = wt_bf + 73728;                  // 16384 bf16 [o][c]
    float* valid = (float*)(gamma_bf + 16384);                 // 524288 fp32 [b][h][w]
    unsigned short* t = (unsigned short*)(valid + 524288);     // bf16 [b][o][h][w]

    sigma_kernel<<<1, 1024, 0, stream>>>(w, u, inv_sigma);
    prep_kernel<<<352, 256, 0, stream>>>(w, gamma, inv_sigma, wt_bf, gamma_bf);
    convgdn_kernel<<<4096, 256, 0, stream>>>(x, mask, wt_bf, bias, gamma_bf, beta, t, valid);
    dwt_kernel<<<32768, 256, 0, stream>>>(t, out);
    dwtmask_kernel<<<512, 256, 0, stream>>>(valid, out);
}